// Round 16
// baseline (132.245 us; speedup 1.0000x reference)
//
#include <hip/hip_runtime.h>

typedef unsigned short u16;
typedef unsigned int u32;
typedef __attribute__((ext_vector_type(8))) __bf16 bf16x8;
typedef __attribute__((ext_vector_type(4))) float f32x4;
typedef __attribute__((ext_vector_type(4))) u16 u16x4;

#define DEVFN static __device__ __forceinline__

constexpr int S_ = 2048;
constexpr int D_ = 1024;
constexpr float SCALE_ = 0.03125f; // 1/sqrt(1024)

DEVFN u16 f2bf(float f) {
  u32 u = __builtin_bit_cast(u32, f);
  return (u16)((u + 0x7fffu + ((u >> 16) & 1u)) >> 16);
}
DEVFN float bf2f(u16 h) {
  u32 u = ((u32)h) << 16;
  return __builtin_bit_cast(float, u);
}
DEVFN void gld16(const u16* g, u16* l) {
  __builtin_amdgcn_global_load_lds(
      (const __attribute__((address_space(1))) u32*)g,
      (__attribute__((address_space(3))) u32*)l, 16, 0, 0);
}

// ---- one-shot conversion kernel: x->bf16 (8192 blk), Wq/Wk->bf16 (2048 blk),
// Wv -> Wv^T bf16 (1024 blk, 32x32 LDS transpose tiles). Grid 11264.
__global__ __launch_bounds__(256) void mega_cvt(const float* __restrict__ x,
                                                const float* __restrict__ Wq,
                                                const float* __restrict__ Wk,
                                                const float* __restrict__ Wv,
                                                u16* __restrict__ Xb,
                                                u16* __restrict__ Wqb,
                                                u16* __restrict__ Wkb,
                                                u16* __restrict__ Wvt) {
  int b = blockIdx.x;
  if (b < 10240) {
    const float* src;
    u16* dst;
    int j;
    if (b < 8192) {
      src = x; dst = Xb; j = b;
    } else if (b < 9216) {
      src = Wq; dst = Wqb; j = b - 8192;
    } else {
      src = Wk; dst = Wkb; j = b - 9216;
    }
    int i = j * 256 + threadIdx.x;
    float4 v = ((const float4*)src)[i];
    u16x4 o = {f2bf(v.x), f2bf(v.y), f2bf(v.z), f2bf(v.w)};
    ((u16x4*)dst)[i] = o;
  } else {
    __shared__ float t[32][33];
    int bb = b - 10240;
    int tx = threadIdx.x & 31, ty = threadIdx.x >> 5; // (32,8)
    int n0 = (bb & 31) * 32, k0 = (bb >> 5) * 32;
#pragma unroll
    for (int i = 0; i < 4; ++i)
      t[ty + i * 8][tx] = Wv[(size_t)(k0 + ty + i * 8) * D_ + n0 + tx];
    __syncthreads();
#pragma unroll
    for (int i = 0; i < 4; ++i)
      Wvt[(size_t)(n0 + ty + i * 8) * D_ + k0 + tx] = f2bf(t[tx][ty + i * 8]);
  }
}

// ---------------- reduce 4 fp32 K-partials -> bf16 Mt ----------------
__global__ __launch_bounds__(256) void reduce_mt_kernel(const float* __restrict__ P4,
                                                        u16* __restrict__ Mt) {
  int i = (blockIdx.x * 256 + threadIdx.x) * 4;
  float4 a = *(const float4*)(P4 + i);
  float4 b = *(const float4*)(P4 + 1048576 + i);
  float4 c = *(const float4*)(P4 + 2097152 + i);
  float4 d = *(const float4*)(P4 + 3145728 + i);
  u16x4 o = {f2bf(a.x + b.x + c.x + d.x), f2bf(a.y + b.y + c.y + d.y),
             f2bf(a.z + b.z + c.z + d.z), f2bf(a.w + b.w + c.w + d.w)};
  *(u16x4*)(Mt + i) = o;
}

// ---------------- merge per-tile row sums -> 1/l per (z,q) ----------------
__global__ __launch_bounds__(256) void merge_inv_kernel(const float* __restrict__ SP,
                                                        float* __restrict__ ST) {
  int idx = blockIdx.x * 256 + threadIdx.x; // 8192 = z*2048+q
  int q = idx & 2047;
  int nt = (q >> 7) + 1;
  const float* p = SP + (size_t)idx * 16;
  float L = 0.f;
  for (int t = 0; t < nt; ++t) L += p[t];
  ST[idx] = 1.0f / L;
}

// ---- 256x256 8-wave 8-phase NT GEMM (proj). R10 structure but with ALL
// sched_barrier(0) pins removed (m141: order-pinning defeats the compiler's
// own fine-grained scheduling). Barriers + volatile waitcnt asm still order
// memory ops; MFMA register dataflow is compiler-tracked; slot hazards are
// unchanged (reads touch slots 2T/2T+1, stages 2T+2/2T+3).
__global__ __launch_bounds__(512, 2) void gemm256_8p(const u16* __restrict__ A,
                                                     const u16* __restrict__ Bt,
                                                     u16* __restrict__ O0,
                                                     u16* __restrict__ O2) {
  int tm = blockIdx.x, tn = blockIdx.y;
  constexpr int NKT = 16; // K-tiles of 64

  __shared__ u16 lsA[4][8192]; // 4 half-slots x 16KB
  __shared__ u16 lsB[4][8192];

  int tid = threadIdx.x;
  int lane = tid & 63, wid = tid >> 6;
  int wm = wid >> 2, wn = wid & 3; // 2(M) x 4(N) waves, 128x64 C each

  const u16* Ab = A + (size_t)tm * 256 * 1024;
  const u16* Bb = Bt + (size_t)tn * 256 * 1024;

  int gsw = tid ^ ((tid >> 3) & 7);
  int grow = gsw >> 3;      // 0..63
  int gcol = (gsw & 7) * 8; // elem col within BK=64

#define STGA(t, h)                                                              \
  do {                                                                          \
    const u16* s_ = Ab + (size_t)((h)*128 + grow) * 1024 + (t)*64 + gcol;       \
    u16* d_ = &lsA[(2 * (t) + (h)) & 3][0] + tid * 8;                           \
    gld16(s_, d_);                                                              \
    gld16(s_ + 65536, d_ + 4096);                                               \
  } while (0)
#define STGB(t, h)                                                              \
  do {                                                                          \
    const u16* s_ = Bb + (size_t)((h)*128 + grow) * 1024 + (t)*64 + gcol;       \
    u16* d_ = &lsB[(2 * (t) + (h)) & 3][0] + tid * 8;                           \
    gld16(s_, d_);                                                              \
    gld16(s_ + 65536, d_ + 4096);                                               \
  } while (0)

  const int kg = lane >> 4;              // 0..3
  const int cs0 = kg ^ (lane & 7);       // swizzled chunk, ks=0
  const int aO0 = (lane & 15) * 64 + cs0 * 8;        // + fm*1024
  const int aO1 = (lane & 15) * 64 + (cs0 ^ 4) * 8;  // ks=1
  const int rb_ = (wn & 1) * 64 + (lane & 15);
  const int bO0 = rb_ * 64 + cs0 * 8;                // + fn*1024
  const int bO1 = rb_ * 64 + (cs0 ^ 4) * 8;

  f32x4 acc[8][4] = {};
  bf16x8 aFa[4], aFb[4], bF0[4], bF1[4];

#define MM(FM, FN, AF, BF)                                                      \
  acc[FM][FN] = __builtin_amdgcn_mfma_f32_16x16x32_bf16(AF, BF, acc[FM][FN], 0, 0, 0)

  STGB(0, 0);
  STGB(0, 1);
  STGA(0, 0);
  STGA(0, 1);
  STGB(1, 0);
  asm volatile("s_waitcnt vmcnt(2)" ::: "memory");
  __builtin_amdgcn_s_barrier();

#pragma unroll 2
  for (int T = 0; T < NKT; ++T) {
    const u16* la = &lsA[(2 * T + wm) & 3][0];
    const u16* lb = &lsB[(2 * T + (wn >> 1)) & 3][0];
    // ---- P1: reads A(fm0-3,ks0)+B(ks0); stage B1(T+1) ----
#pragma unroll
    for (int f = 0; f < 4; ++f) {
      aFa[f] = *(const bf16x8*)(la + aO0 + f * 1024);
      bF0[f] = *(const bf16x8*)(lb + bO0 + f * 1024);
    }
    if (T + 1 < NKT) STGB(T + 1, 1);
    __builtin_amdgcn_s_barrier();
    __builtin_amdgcn_s_setprio(1);
#pragma unroll
    for (int fm = 0; fm < 4; ++fm)
#pragma unroll
      for (int fn = 0; fn < 4; ++fn) MM(fm, fn, aFa[fm], bF0[fn]);
    __builtin_amdgcn_s_setprio(0);
    // ---- P2: reads A(fm4-7,ks0); stage A1(T+1) ----
#pragma unroll
    for (int f = 0; f < 4; ++f)
      aFb[f] = *(const bf16x8*)(la + aO0 + (f + 4) * 1024);
    if (T + 1 < NKT) STGA(T + 1, 1);
    __builtin_amdgcn_s_barrier();
    __builtin_amdgcn_s_setprio(1);
#pragma unroll
    for (int fm = 0; fm < 4; ++fm)
#pragma unroll
      for (int fn = 0; fn < 4; ++fn) MM(fm + 4, fn, aFb[fm], bF0[fn]);
    __builtin_amdgcn_s_setprio(0);
    // ---- P3: reads A(fm0-3,ks1)+B(ks1); stage A0(T+1) ----
#pragma unroll
    for (int f = 0; f < 4; ++f) {
      aFa[f] = *(const bf16x8*)(la + aO1 + f * 1024);
      bF1[f] = *(const bf16x8*)(lb + bO1 + f * 1024);
    }
    if (T + 1 < NKT) STGA(T + 1, 0);
    __builtin_amdgcn_s_barrier();
    __builtin_amdgcn_s_setprio(1);
#pragma unroll
    for (int fm = 0; fm < 4; ++fm)
#pragma unroll
      for (int fn = 0; fn < 4; ++fn) MM(fm, fn, aFa[fm], bF1[fn]);
    __builtin_amdgcn_s_setprio(0);
    // ---- P4: reads A(fm4-7,ks1); stage B0(T+2); vmcnt(2) boundary ----
#pragma unroll
    for (int f = 0; f < 4; ++f)
      aFb[f] = *(const bf16x8*)(la + aO1 + (f + 4) * 1024);
    if (T + 2 < NKT) {
      STGB(T + 2, 0);
      asm volatile("s_waitcnt vmcnt(2)" ::: "memory");
    } else {
      asm volatile("s_waitcnt vmcnt(0)" ::: "memory");
    }
    __builtin_amdgcn_s_barrier();
    __builtin_amdgcn_s_setprio(1);
#pragma unroll
    for (int fm = 0; fm < 4; ++fm)
#pragma unroll
      for (int fn = 0; fn < 4; ++fn) MM(fm + 4, fn, aFb[fm], bF1[fn]);
    __builtin_amdgcn_s_setprio(0);
  }

#undef MM
#undef STGA
#undef STGB

  int r0 = tm * 256 + wm * 128 + (lane >> 4) * 4;
  int c0 = tn * 256 + wn * 64 + (lane & 15);

  if (tn < 4) { // X-tilde, row-major [8192][1024]
#pragma unroll
    for (int fm = 0; fm < 8; ++fm)
#pragma unroll
      for (int fn = 0; fn < 4; ++fn)
#pragma unroll
        for (int i = 0; i < 4; ++i)
          O0[(size_t)(r0 + fm * 16 + i) * 1024 + (c0 + fn * 16)] =
              f2bf(acc[fm][fn][i]);
  } else { // V transposed: Vt[b][e][s]
#pragma unroll
    for (int fm = 0; fm < 8; ++fm)
#pragma unroll
      for (int fn = 0; fn < 4; ++fn) {
        int r = r0 + fm * 16;
        int bb = r >> 11, s0 = r & 2047;
        int e = c0 + fn * 16 - 1024;
        u16x4 o = {f2bf(acc[fm][fn][0]), f2bf(acc[fm][fn][1]),
                   f2bf(acc[fm][fn][2]), f2bf(acc[fm][fn][3])};
        *(u16x4*)(O2 + (size_t)bb * 2097152 + (size_t)e * 2048 + s0) = o;
      }
  }
}

// ---- 128x128 4-wave NT GEMM, BK=32, NBUF ring ----
// MODE 2: scores A=Xt, Bt=Xb per batch (K=1024); writes Pm = bf16(exp(s*scale))
//         causally masked to 0, + per-tile row sums -> SP[(z*2048+q)*16+tn].
//         544-block triangular grid: z=id&3, tri=id>>2.
// MODE 3: PV A=Pm(exp'd), Bt=Vt per batch, out = (P.V) * ST[row] (fp32).
// MODE 4: Mt-partial: A=Wkb, Bt=Wqb (K-chunk z*256..+256), fp32 partial out.
template <int MODE, int NBUF>
__global__ __launch_bounds__(256, NBUF == 3 ? 3 : 2) void
gemm128(const u16* __restrict__ A, const u16* __restrict__ Bt,
        u16* __restrict__ O0, float* __restrict__ OF, float* __restrict__ SX) {
  int tm, tn, z;
  if (MODE == 3) {
    int id = blockIdx.x; // 512 blocks: tn(3b) | z(2b) | tmh(4b)
    tn = id & 7;
    z = (id >> 3) & 3;
    int tmh = id >> 5; // blocks id, id+256 get tm summing to 15
    tm = (tmh < 8) ? tmh : 23 - tmh;
  } else if (MODE == 2) {
    int id = blockIdx.x; // 544 blocks = 136 triangular tiles x 4 batches
    z = id & 3;
    int tri = id >> 2;
    int r = (int)((sqrtf(8.0f * (float)tri + 1.0f) - 1.0f) * 0.5f);
    while ((r + 1) * (r + 2) / 2 <= tri) ++r;
    while (r * (r + 1) / 2 > tri) --r;
    tm = r;
    tn = tri - r * (r + 1) / 2;
  } else {
    tm = blockIdx.x;
    tn = blockIdx.y;
    z = blockIdx.z;
  }
  constexpr int LDA = (MODE == 3) ? 2048 : 1024;
  constexpr int LDB = (MODE == 3) ? 2048 : 1024;
  const int NKT = (MODE == 3) ? (tm + 1) * 4 : (MODE == 4 ? 8 : 32);

  __shared__ u16 ls[NBUF][2][4096]; // NBUF x {A,B} x 8KB

  int tid = threadIdx.x;
  int lane = tid & 63, wid = tid >> 6;
  int wm = wid >> 1, wn = wid & 1; // 2(M) x 2(N) waves, 64x64 each

  const u16* Ab = A +
      (MODE == 2 ? (size_t)z * (2048 * 1024)
                 : (MODE == 3 ? (size_t)z * (2048 * 2048) : (size_t)0)) +
      (MODE == 4 ? z * 256 : 0) + (size_t)tm * 128 * LDA;
  const u16* Bb = Bt +
      (MODE == 2 ? (size_t)z * (2048 * 1024)
                 : (MODE == 3 ? (size_t)z * (1024 * 2048) : (size_t)0)) +
      (MODE == 4 ? z * 256 : 0) + (size_t)tn * 128 * LDB;

  int gsw = tid ^ ((tid >> 3) & 7);
  int sr = gsw >> 2;      // 0..63
  int sc = (gsw & 3) * 8; // k-offset (elements)

#define STG(bf, kt)                                                             \
  do {                                                                          \
    int k0_ = (kt) * 32;                                                        \
    gld16(Ab + (size_t)sr * LDA + k0_ + sc, &ls[bf][0][0] + tid * 8);           \
    gld16(Ab + (size_t)(sr + 64) * LDA + k0_ + sc,                              \
          &ls[bf][0][0] + 2048 + tid * 8);                                      \
    gld16(Bb + (size_t)sr * LDB + k0_ + sc, &ls[bf][1][0] + tid * 8);           \
    gld16(Bb + (size_t)(sr + 64) * LDB + k0_ + sc,                              \
          &ls[bf][1][0] + 2048 + tid * 8);                                      \
  } while (0)

  const int kg_ = lane >> 4;
  const int arow = wm * 64 + (lane & 15);
  const int brow = wn * 64 + (lane & 15);
  const int aoff = ((arow * 4 + kg_) ^ ((arow >> 1) & 7)) * 8;
  const int boff = ((brow * 4 + kg_) ^ ((brow >> 1) & 7)) * 8;

  f32x4 acc[4][4] = {};
  int rb = 0, wb = 2; // NBUF==3 ring bookkeeping

  STG(0, 0);
  STG(1, 1);
  if (NBUF == 4) STG(2, 2);

#define KSTEP(t, W)                                                             \
  do {                                                                          \
    asm volatile("s_waitcnt vmcnt(%0)" ::"n"(W) : "memory");                    \
    __builtin_amdgcn_s_barrier();                                               \
    __builtin_amdgcn_sched_barrier(0);                                          \
    if (NBUF == 4) {                                                            \
      if ((t) + 3 < NKT) STG(((t) + 3) & 3, (t) + 3);                           \
    } else {                                                                    \
      if ((t) + 2 < NKT) STG(wb, (t) + 2);                                      \
    }                                                                           \
    const u16* la_ = &ls[(NBUF == 4) ? ((t) & 3) : rb][0][0] + aoff;            \
    const u16* lb_ = &ls[(NBUF == 4) ? ((t) & 3) : rb][1][0] + boff;            \
    bf16x8 aF[4], bF[4];                                                        \
    _Pragma("unroll") for (int f = 0; f < 4; ++f)                               \
        aF[f] = *(const bf16x8*)(la_ + f * 512);                                \
    _Pragma("unroll") for (int f = 0; f < 4; ++f)                               \
        bF[f] = *(const bf16x8*)(lb_ + f * 512);                                \
    __builtin_amdgcn_s_setprio(1);                                              \
    _Pragma("unroll") for (int fm = 0; fm < 4; ++fm)                            \
        _Pragma("unroll") for (int fn = 0; fn < 4; ++fn)                        \
            acc[fm][fn] = __builtin_amdgcn_mfma_f32_16x16x32_bf16(              \
                aF[fm], bF[fn], acc[fm][fn], 0, 0, 0);                          \
    __builtin_amdgcn_s_setprio(0);                                              \
    if (NBUF == 3) {                                                            \
      rb = (rb == 2) ? 0 : rb + 1;                                              \
      wb = (wb == 2) ? 0 : wb + 1;                                              \
    }                                                                           \
  } while (0)

  if (NBUF == 4) {
    for (int t = 0; t < NKT - 2; ++t) KSTEP(t, 8);
    KSTEP(NKT - 2, 4);
    KSTEP(NKT - 1, 0);
  } else {
    for (int t = 0; t < NKT - 1; ++t) KSTEP(t, 4);
    KSTEP(NKT - 1, 0);
  }

#undef KSTEP
#undef STG

  // ---- epilogue ----
  int r0 = tm * 128 + wm * 64 + (lane >> 4) * 4;
  int c0 = tn * 128 + wn * 64 + (lane & 15);

  if (MODE == 2) {
    // write exp'd, causally-masked P + per-tile row sums
    u16* P = O0 + (size_t)z * 4194304;
    float* sst = (float*)&ls[0][0][0]; // 128 rows x 2 (wn)
#pragma unroll
    for (int fm = 0; fm < 4; ++fm)
#pragma unroll
      for (int i = 0; i < 4; ++i) {
        int rg = r0 + fm * 16 + i;
        float lv = 0.f;
        u16 w4[4];
#pragma unroll
        for (int fn = 0; fn < 4; ++fn) {
          int cg = c0 + fn * 16;
          float p = (cg <= rg) ? __expf(acc[fm][fn][i] * SCALE_) : 0.f;
          w4[fn] = f2bf(p);
          lv += p;
        }
#pragma unroll
        for (int fn = 0; fn < 4; ++fn)
          P[(size_t)rg * 2048 + (c0 + fn * 16)] = w4[fn];
#pragma unroll
        for (int off = 1; off < 16; off <<= 1) lv += __shfl_xor(lv, off, 64);
        if ((lane & 15) == 0) sst[(rg - tm * 128) * 2 + wn] = lv;
      }
    __syncthreads();
    if (tid < 128) {
      float s = sst[tid * 2] + sst[tid * 2 + 1];
      SX[((size_t)z * 2048 + tm * 128 + tid) * 16 + tn] = s;
    }
  } else if (MODE == 4) {
    float* Ob = OF + (size_t)z * 1048576;
#pragma unroll
    for (int fm = 0; fm < 4; ++fm)
#pragma unroll
      for (int fn = 0; fn < 4; ++fn)
#pragma unroll
        for (int i = 0; i < 4; ++i)
          Ob[(size_t)(r0 + fm * 16 + i) * 1024 + (c0 + fn * 16)] = acc[fm][fn][i];
  } else { // MODE 3: scale by ST[row] = 1/l
    float* Ob = OF + (size_t)z * 2097152;
    const float* IL = SX + (size_t)z * 2048;
#pragma unroll
    for (int fm = 0; fm < 4; ++fm)
#pragma unroll
      for (int i = 0; i < 4; ++i) {
        float il = IL[r0 + fm * 16 + i];
#pragma unroll
        for (int fn = 0; fn < 4; ++fn)
          Ob[(size_t)(r0 + fm * 16 + i) * 1024 + (c0 + fn * 16)] =
              acc[fm][fn][i] * il;
      }
  }
}

extern "C" void kernel_launch(void* const* d_in, const int* in_sizes, int n_in,
                              void* d_out, int out_size, void* d_ws, size_t ws_size,
                              hipStream_t stream) {
  const float* x = (const float*)d_in[0];
  const float* Wq = (const float*)d_in[1];
  const float* Wk = (const float*)d_in[2];
  const float* Wv = (const float*)d_in[3];
  float* out = (float*)d_out;

  u16* ws = (u16*)d_ws;
  u16* Xb = ws;               // [8192][1024] bf16
  u16* Xt = ws + 8388608;     // [8192][1024] bf16 (X * WqWk^T)
  u16* Wqb = ws + 16777216;   // [1024][1024] bf16
  u16* Wkb = ws + 17825792;   // [1024][1024] bf16
  u16* Vt = ws + 25165824;    // [4][1024][2048] bf16 (e-major)
  u16* Pm = ws + 33554432;    // [4][2048][2048] bf16 exp'd scores
  float* Pp = (float*)(ws + 33554432); // [4][1024][1024] fp32 Mt partials (dead before Pm)
  u16* Wcat = ws + 50331648;  // [2048][1024]: Mt | Wv^T
  u16* Mt = Wcat;
  u16* Wvt = Wcat + 1048576;
  float* SP = (float*)(ws + 52428800); // [8192][16] per-tile row sums
  float* ST = (float*)(ws + 52953088); // [8192] 1/l

  // all input conversions in one launch
  mega_cvt<<<11264, 256, 0, stream>>>(x, Wq, Wk, Wv, Xb, Wqb, Wkb, Wvt);

  // Mt = Wk * Wq^T, K-split over 4 chunks, then reduce to bf16
  gemm128<4, 4><<<dim3(8, 8, 4), 256, 0, stream>>>(Wkb, Wqb, nullptr, Pp, nullptr);
  reduce_mt_kernel<<<1024, 256, 0, stream>>>(Pp, Mt);

  // fused proj: [Xt | V] = Xb * [Mt | Wvt]^T ; 256 blocks = 1 round, 8-phase
  gemm256_8p<<<dim3(32, 8), 512, 0, stream>>>(Xb, Wcat, Xt, Vt);

  // scores: Pm = exp(Xt * Xb^T * scale), masked; + row-sum partials SP
  gemm128<2, 3><<<dim3(544, 1, 1), 256, 0, stream>>>(Xt, Xb, Pm, nullptr, SP);

  merge_inv_kernel<<<32, 256, 0, stream>>>(SP, ST);

  // PV: out = (Pm . Vt^T) * invl ; 512 blocks, paired tm for balance
  gemm128<3, 4><<<dim3(512, 1, 1), 256, 0, stream>>>(Pm, Vt, nullptr, out, ST);
}

// Round 17
// 131.124 us; speedup vs baseline: 1.0085x; 1.0085x over previous
//
#include <hip/hip_runtime.h>

typedef unsigned short u16;
typedef unsigned int u32;
typedef __attribute__((ext_vector_type(8))) __bf16 bf16x8;
typedef __attribute__((ext_vector_type(4))) float f32x4;
typedef __attribute__((ext_vector_type(4))) u16 u16x4;

#define DEVFN static __device__ __forceinline__

constexpr int S_ = 2048;
constexpr int D_ = 1024;
constexpr float SCALE_ = 0.03125f; // 1/sqrt(1024)

DEVFN u16 f2bf(float f) {
  u32 u = __builtin_bit_cast(u32, f);
  return (u16)((u + 0x7fffu + ((u >> 16) & 1u)) >> 16);
}
DEVFN float bf2f(u16 h) {
  u32 u = ((u32)h) << 16;
  return __builtin_bit_cast(float, u);
}
DEVFN void gld16(const u16* g, u16* l) {
  __builtin_amdgcn_global_load_lds(
      (const __attribute__((address_space(1))) u32*)g,
      (__attribute__((address_space(3))) u32*)l, 16, 0, 0);
}

// ---- one-shot conversion kernel: x->bf16 (8192 blk), Wq/Wk->bf16 (2048 blk),
// Wv -> Wv^T bf16 (1024 blk, 32x32 LDS transpose tiles). Grid 11264.
__global__ __launch_bounds__(256) void mega_cvt(const float* __restrict__ x,
                                                const float* __restrict__ Wq,
                                                const float* __restrict__ Wk,
                                                const float* __restrict__ Wv,
                                                u16* __restrict__ Xb,
                                                u16* __restrict__ Wqb,
                                                u16* __restrict__ Wkb,
                                                u16* __restrict__ Wvt) {
  int b = blockIdx.x;
  if (b < 10240) {
    const float* src;
    u16* dst;
    int j;
    if (b < 8192) {
      src = x; dst = Xb; j = b;
    } else if (b < 9216) {
      src = Wq; dst = Wqb; j = b - 8192;
    } else {
      src = Wk; dst = Wkb; j = b - 9216;
    }
    int i = j * 256 + threadIdx.x;
    float4 v = ((const float4*)src)[i];
    u16x4 o = {f2bf(v.x), f2bf(v.y), f2bf(v.z), f2bf(v.w)};
    ((u16x4*)dst)[i] = o;
  } else {
    __shared__ float t[32][33];
    int bb = b - 10240;
    int tx = threadIdx.x & 31, ty = threadIdx.x >> 5; // (32,8)
    int n0 = (bb & 31) * 32, k0 = (bb >> 5) * 32;
#pragma unroll
    for (int i = 0; i < 4; ++i)
      t[ty + i * 8][tx] = Wv[(size_t)(k0 + ty + i * 8) * D_ + n0 + tx];
    __syncthreads();
#pragma unroll
    for (int i = 0; i < 4; ++i)
      Wvt[(size_t)(n0 + ty + i * 8) * D_ + k0 + tx] = f2bf(t[tx][ty + i * 8]);
  }
}

// ---------------- reduce 4 fp32 K-partials -> bf16 Mt ----------------
__global__ __launch_bounds__(256) void reduce_mt_kernel(const float* __restrict__ P4,
                                                        u16* __restrict__ Mt) {
  int i = (blockIdx.x * 256 + threadIdx.x) * 4;
  float4 a = *(const float4*)(P4 + i);
  float4 b = *(const float4*)(P4 + 1048576 + i);
  float4 c = *(const float4*)(P4 + 2097152 + i);
  float4 d = *(const float4*)(P4 + 3145728 + i);
  u16x4 o = {f2bf(a.x + b.x + c.x + d.x), f2bf(a.y + b.y + c.y + d.y),
             f2bf(a.z + b.z + c.z + d.z), f2bf(a.w + b.w + c.w + d.w)};
  *(u16x4*)(Mt + i) = o;
}

// ---------------- merge per-tile row sums -> 1/l per (z,q) ----------------
__global__ __launch_bounds__(256) void merge_inv_kernel(const float* __restrict__ SP,
                                                        float* __restrict__ ST) {
  int idx = blockIdx.x * 256 + threadIdx.x; // 8192 = z*2048+q
  int q = idx & 2047;
  int nt = (q >> 7) + 1;
  const float* p = SP + (size_t)idx * 16;
  float L = 0.f;
  for (int t = 0; t < nt; ++t) L += p[t];
  ST[idx] = 1.0f / L;
}

// ---- 256x256 8-wave 8-phase NT GEMM (proj), 810 TF structure ceiling ----
__global__ __launch_bounds__(512, 2) void gemm256_8p(const u16* __restrict__ A,
                                                     const u16* __restrict__ Bt,
                                                     u16* __restrict__ O0,
                                                     u16* __restrict__ O2) {
  int tm = blockIdx.x, tn = blockIdx.y;
  constexpr int NKT = 16; // K-tiles of 64

  __shared__ u16 lsA[4][8192]; // 4 half-slots x 16KB
  __shared__ u16 lsB[4][8192];

  int tid = threadIdx.x;
  int lane = tid & 63, wid = tid >> 6;
  int wm = wid >> 2, wn = wid & 3; // 2(M) x 4(N) waves, 128x64 C each

  const u16* Ab = A + (size_t)tm * 256 * 1024;
  const u16* Bb = Bt + (size_t)tn * 256 * 1024;

  int gsw = tid ^ ((tid >> 3) & 7);
  int grow = gsw >> 3;      // 0..63
  int gcol = (gsw & 7) * 8; // elem col within BK=64

#define STGA(t, h)                                                              \
  do {                                                                          \
    const u16* s_ = Ab + (size_t)((h)*128 + grow) * 1024 + (t)*64 + gcol;       \
    u16* d_ = &lsA[(2 * (t) + (h)) & 3][0] + tid * 8;                           \
    gld16(s_, d_);                                                              \
    gld16(s_ + 65536, d_ + 4096);                                               \
  } while (0)
#define STGB(t, h)                                                              \
  do {                                                                          \
    const u16* s_ = Bb + (size_t)((h)*128 + grow) * 1024 + (t)*64 + gcol;       \
    u16* d_ = &lsB[(2 * (t) + (h)) & 3][0] + tid * 8;                           \
    gld16(s_, d_);                                                              \
    gld16(s_ + 65536, d_ + 4096);                                               \
  } while (0)

  const int kg = lane >> 4;              // 0..3
  const int cs0 = kg ^ (lane & 7);       // swizzled chunk, ks=0
  const int aO0 = (lane & 15) * 64 + cs0 * 8;        // + fm*1024
  const int aO1 = (lane & 15) * 64 + (cs0 ^ 4) * 8;  // ks=1
  const int rb_ = (wn & 1) * 64 + (lane & 15);
  const int bO0 = rb_ * 64 + cs0 * 8;                // + fn*1024
  const int bO1 = rb_ * 64 + (cs0 ^ 4) * 8;

  f32x4 acc[8][4] = {};
  bf16x8 aFa[4], aFb[4], bF0[4], bF1[4];

#define MM(FM, FN, AF, BF)                                                      \
  acc[FM][FN] = __builtin_amdgcn_mfma_f32_16x16x32_bf16(AF, BF, acc[FM][FN], 0, 0, 0)

  STGB(0, 0);
  STGB(0, 1);
  STGA(0, 0);
  STGA(0, 1);
  STGB(1, 0);
  asm volatile("s_waitcnt vmcnt(2)" ::: "memory");
  __builtin_amdgcn_s_barrier();

#pragma unroll 2
  for (int T = 0; T < NKT; ++T) {
    const u16* la = &lsA[(2 * T + wm) & 3][0];
    const u16* lb = &lsB[(2 * T + (wn >> 1)) & 3][0];
    // ---- P1: reads A(fm0-3,ks0)+B(ks0); stage B1(T+1) ----
#pragma unroll
    for (int f = 0; f < 4; ++f) {
      aFa[f] = *(const bf16x8*)(la + aO0 + f * 1024);
      bF0[f] = *(const bf16x8*)(lb + bO0 + f * 1024);
    }
    if (T + 1 < NKT) STGB(T + 1, 1);
    __builtin_amdgcn_s_barrier();
    __builtin_amdgcn_s_setprio(1);
#pragma unroll
    for (int fm = 0; fm < 4; ++fm)
#pragma unroll
      for (int fn = 0; fn < 4; ++fn) MM(fm, fn, aFa[fm], bF0[fn]);
    __builtin_amdgcn_s_setprio(0);
    // ---- P2: reads A(fm4-7,ks0); stage A1(T+1) ----
#pragma unroll
    for (int f = 0; f < 4; ++f)
      aFb[f] = *(const bf16x8*)(la + aO0 + (f + 4) * 1024);
    if (T + 1 < NKT) STGA(T + 1, 1);
    __builtin_amdgcn_s_barrier();
    __builtin_amdgcn_s_setprio(1);
#pragma unroll
    for (int fm = 0; fm < 4; ++fm)
#pragma unroll
      for (int fn = 0; fn < 4; ++fn) MM(fm + 4, fn, aFb[fm], bF0[fn]);
    __builtin_amdgcn_s_setprio(0);
    // ---- P3: reads A(fm0-3,ks1)+B(ks1); stage A0(T+1) ----
#pragma unroll
    for (int f = 0; f < 4; ++f) {
      aFa[f] = *(const bf16x8*)(la + aO1 + f * 1024);
      bF1[f] = *(const bf16x8*)(lb + bO1 + f * 1024);
    }
    if (T + 1 < NKT) STGA(T + 1, 0);
    __builtin_amdgcn_s_barrier();
    __builtin_amdgcn_s_setprio(1);
#pragma unroll
    for (int fm = 0; fm < 4; ++fm)
#pragma unroll
      for (int fn = 0; fn < 4; ++fn) MM(fm, fn, aFa[fm], bF1[fn]);
    __builtin_amdgcn_s_setprio(0);
    // ---- P4: reads A(fm4-7,ks1); stage B0(T+2); vmcnt(2) boundary ----
#pragma unroll
    for (int f = 0; f < 4; ++f)
      aFb[f] = *(const bf16x8*)(la + aO1 + (f + 4) * 1024);
    if (T + 2 < NKT) {
      STGB(T + 2, 0);
      asm volatile("s_waitcnt vmcnt(2)" ::: "memory");
    } else {
      asm volatile("s_waitcnt vmcnt(0)" ::: "memory");
    }
    __builtin_amdgcn_s_barrier();
    __builtin_amdgcn_s_setprio(1);
#pragma unroll
    for (int fm = 0; fm < 4; ++fm)
#pragma unroll
      for (int fn = 0; fn < 4; ++fn) MM(fm + 4, fn, aFb[fm], bF1[fn]);
    __builtin_amdgcn_s_setprio(0);
  }

#undef MM
#undef STGA
#undef STGB

  int r0 = tm * 256 + wm * 128 + (lane >> 4) * 4;
  int c0 = tn * 256 + wn * 64 + (lane & 15);

  if (tn < 4) { // X-tilde, row-major [8192][1024]
#pragma unroll
    for (int fm = 0; fm < 8; ++fm)
#pragma unroll
      for (int fn = 0; fn < 4; ++fn)
#pragma unroll
        for (int i = 0; i < 4; ++i)
          O0[(size_t)(r0 + fm * 16 + i) * 1024 + (c0 + fn * 16)] =
              f2bf(acc[fm][fn][i]);
  } else { // V transposed: Vt[b][e][s]
#pragma unroll
    for (int fm = 0; fm < 8; ++fm)
#pragma unroll
      for (int fn = 0; fn < 4; ++fn) {
        int r = r0 + fm * 16;
        int bb = r >> 11, s0 = r & 2047;
        int e = c0 + fn * 16 - 1024;
        u16x4 o = {f2bf(acc[fm][fn][0]), f2bf(acc[fm][fn][1]),
                   f2bf(acc[fm][fn][2]), f2bf(acc[fm][fn][3])};
        *(u16x4*)(O2 + (size_t)bb * 2097152 + (size_t)e * 2048 + s0) = o;
      }
  }
}

// ---- 128x128 4-wave NT GEMM, BK=32, NBUF ring ----
// MODE 2: scores A=Xt, Bt=Xb per batch (K=1024); writes Pm = bf16(exp(s*scale))
//         causally masked to 0, + per-tile row sums -> SP[(z*2048+q)*16+tn].
//         544-block triangular grid: z=id&3, tri=id>>2.
// MODE 3: PV A=Pm(exp'd), Bt=Vt per batch, out = (P.V) * ST[row] (fp32).
//         NBUF=3 -> 48KB LDS -> 3 blocks/CU (matches scores' occupancy).
// MODE 4: Mt-partial: A=Wkb, Bt=Wqb (K-chunk z*256..+256), fp32 partial out.
template <int MODE, int NBUF>
__global__ __launch_bounds__(256, NBUF == 3 ? 3 : 2) void
gemm128(const u16* __restrict__ A, const u16* __restrict__ Bt,
        u16* __restrict__ O0, float* __restrict__ OF, float* __restrict__ SX) {
  int tm, tn, z;
  if (MODE == 3) {
    int id = blockIdx.x; // 512 blocks: tn(3b) | z(2b) | tmh(4b)
    tn = id & 7;
    z = (id >> 3) & 3;
    int tmh = id >> 5; // blocks id, id+256 get tm summing to 15
    tm = (tmh < 8) ? tmh : 23 - tmh;
  } else if (MODE == 2) {
    int id = blockIdx.x; // 544 blocks = 136 triangular tiles x 4 batches
    z = id & 3;
    int tri = id >> 2;
    int r = (int)((sqrtf(8.0f * (float)tri + 1.0f) - 1.0f) * 0.5f);
    while ((r + 1) * (r + 2) / 2 <= tri) ++r;
    while (r * (r + 1) / 2 > tri) --r;
    tm = r;
    tn = tri - r * (r + 1) / 2;
  } else {
    tm = blockIdx.x;
    tn = blockIdx.y;
    z = blockIdx.z;
  }
  constexpr int LDA = (MODE == 3) ? 2048 : 1024;
  constexpr int LDB = (MODE == 3) ? 2048 : 1024;
  const int NKT = (MODE == 3) ? (tm + 1) * 4 : (MODE == 4 ? 8 : 32);

  __shared__ u16 ls[NBUF][2][4096]; // NBUF x {A,B} x 8KB

  int tid = threadIdx.x;
  int lane = tid & 63, wid = tid >> 6;
  int wm = wid >> 1, wn = wid & 1; // 2(M) x 2(N) waves, 64x64 each

  const u16* Ab = A +
      (MODE == 2 ? (size_t)z * (2048 * 1024)
                 : (MODE == 3 ? (size_t)z * (2048 * 2048) : (size_t)0)) +
      (MODE == 4 ? z * 256 : 0) + (size_t)tm * 128 * LDA;
  const u16* Bb = Bt +
      (MODE == 2 ? (size_t)z * (2048 * 1024)
                 : (MODE == 3 ? (size_t)z * (1024 * 2048) : (size_t)0)) +
      (MODE == 4 ? z * 256 : 0) + (size_t)tn * 128 * LDB;

  int gsw = tid ^ ((tid >> 3) & 7);
  int sr = gsw >> 2;      // 0..63
  int sc = (gsw & 3) * 8; // k-offset (elements)

#define STG(bf, kt)                                                             \
  do {                                                                          \
    int k0_ = (kt) * 32;                                                        \
    gld16(Ab + (size_t)sr * LDA + k0_ + sc, &ls[bf][0][0] + tid * 8);           \
    gld16(Ab + (size_t)(sr + 64) * LDA + k0_ + sc,                              \
          &ls[bf][0][0] + 2048 + tid * 8);                                      \
    gld16(Bb + (size_t)sr * LDB + k0_ + sc, &ls[bf][1][0] + tid * 8);           \
    gld16(Bb + (size_t)(sr + 64) * LDB + k0_ + sc,                              \
          &ls[bf][1][0] + 2048 + tid * 8);                                      \
  } while (0)

  const int kg_ = lane >> 4;
  const int arow = wm * 64 + (lane & 15);
  const int brow = wn * 64 + (lane & 15);
  const int aoff = ((arow * 4 + kg_) ^ ((arow >> 1) & 7)) * 8;
  const int boff = ((brow * 4 + kg_) ^ ((brow >> 1) & 7)) * 8;

  f32x4 acc[4][4] = {};
  int rb = 0, wb = 2; // NBUF==3 ring bookkeeping

  STG(0, 0);
  STG(1, 1);
  if (NBUF == 4) STG(2, 2);

#define KSTEP(t, W)                                                             \
  do {                                                                          \
    asm volatile("s_waitcnt vmcnt(%0)" ::"n"(W) : "memory");                    \
    __builtin_amdgcn_s_barrier();                                               \
    __builtin_amdgcn_sched_barrier(0);                                          \
    if (NBUF == 4) {                                                            \
      if ((t) + 3 < NKT) STG(((t) + 3) & 3, (t) + 3);                           \
    } else {                                                                    \
      if ((t) + 2 < NKT) STG(wb, (t) + 2);                                      \
    }                                                                           \
    const u16* la_ = &ls[(NBUF == 4) ? ((t) & 3) : rb][0][0] + aoff;            \
    const u16* lb_ = &ls[(NBUF == 4) ? ((t) & 3) : rb][1][0] + boff;            \
    bf16x8 aF[4], bF[4];                                                        \
    _Pragma("unroll") for (int f = 0; f < 4; ++f)                               \
        aF[f] = *(const bf16x8*)(la_ + f * 512);                                \
    _Pragma("unroll") for (int f = 0; f < 4; ++f)                               \
        bF[f] = *(const bf16x8*)(lb_ + f * 512);                                \
    __builtin_amdgcn_s_setprio(1);                                              \
    _Pragma("unroll") for (int fm = 0; fm < 4; ++fm)                            \
        _Pragma("unroll") for (int fn = 0; fn < 4; ++fn)                        \
            acc[fm][fn] = __builtin_amdgcn_mfma_f32_16x16x32_bf16(              \
                aF[fm], bF[fn], acc[fm][fn], 0, 0, 0);                          \
    __builtin_amdgcn_s_setprio(0);                                              \
    if (NBUF == 3) {                                                            \
      rb = (rb == 2) ? 0 : rb + 1;                                              \
      wb = (wb == 2) ? 0 : wb + 1;                                              \
    }                                                                           \
  } while (0)

  if (NBUF == 4) {
    for (int t = 0; t < NKT - 2; ++t) KSTEP(t, 8);
    KSTEP(NKT - 2, 4);
    KSTEP(NKT - 1, 0);
  } else {
    for (int t = 0; t < NKT - 1; ++t) KSTEP(t, 4);
    KSTEP(NKT - 1, 0);
  }

#undef KSTEP
#undef STG

  // ---- epilogue ----
  int r0 = tm * 128 + wm * 64 + (lane >> 4) * 4;
  int c0 = tn * 128 + wn * 64 + (lane & 15);

  if (MODE == 2) {
    // write exp'd, causally-masked P + per-tile row sums
    u16* P = O0 + (size_t)z * 4194304;
    float* sst = (float*)&ls[0][0][0]; // 128 rows x 2 (wn)
#pragma unroll
    for (int fm = 0; fm < 4; ++fm)
#pragma unroll
      for (int i = 0; i < 4; ++i) {
        int rg = r0 + fm * 16 + i;
        float lv = 0.f;
        u16 w4[4];
#pragma unroll
        for (int fn = 0; fn < 4; ++fn) {
          int cg = c0 + fn * 16;
          float p = (cg <= rg) ? __expf(acc[fm][fn][i] * SCALE_) : 0.f;
          w4[fn] = f2bf(p);
          lv += p;
        }
#pragma unroll
        for (int fn = 0; fn < 4; ++fn)
          P[(size_t)rg * 2048 + (c0 + fn * 16)] = w4[fn];
#pragma unroll
        for (int off = 1; off < 16; off <<= 1) lv += __shfl_xor(lv, off, 64);
        if ((lane & 15) == 0) sst[(rg - tm * 128) * 2 + wn] = lv;
      }
    __syncthreads();
    if (tid < 128) {
      float s = sst[tid * 2] + sst[tid * 2 + 1];
      SX[((size_t)z * 2048 + tm * 128 + tid) * 16 + tn] = s;
    }
  } else if (MODE == 4) {
    float* Ob = OF + (size_t)z * 1048576;
#pragma unroll
    for (int fm = 0; fm < 4; ++fm)
#pragma unroll
      for (int fn = 0; fn < 4; ++fn)
#pragma unroll
        for (int i = 0; i < 4; ++i)
          Ob[(size_t)(r0 + fm * 16 + i) * 1024 + (c0 + fn * 16)] = acc[fm][fn][i];
  } else { // MODE 3: scale by ST[row] = 1/l
    float* Ob = OF + (size_t)z * 2097152;
    const float* IL = SX + (size_t)z * 2048;
#pragma unroll
    for (int fm = 0; fm < 4; ++fm)
#pragma unroll
      for (int i = 0; i < 4; ++i) {
        float il = IL[r0 + fm * 16 + i];
#pragma unroll
        for (int fn = 0; fn < 4; ++fn)
          Ob[(size_t)(r0 + fm * 16 + i) * 1024 + (c0 + fn * 16)] =
              acc[fm][fn][i] * il;
      }
  }
}

extern "C" void kernel_launch(void* const* d_in, const int* in_sizes, int n_in,
                              void* d_out, int out_size, void* d_ws, size_t ws_size,
                              hipStream_t stream) {
  const float* x = (const float*)d_in[0];
  const float* Wq = (const float*)d_in[1];
  const float* Wk = (const float*)d_in[2];
  const float* Wv = (const float*)d_in[3];
  float* out = (float*)d_out;

  u16* ws = (u16*)d_ws;
  u16* Xb = ws;               // [8192][1024] bf16
  u16* Xt = ws + 8388608;     // [8192][1024] bf16 (X * WqWk^T)
  u16* Wqb = ws + 16777216;   // [1024][1024] bf16
  u16* Wkb = ws + 17825792;   // [1024][1024] bf16
  u16* Vt = ws + 25165824;    // [4][1024][2048] bf16 (e-major)
  u16* Pm = ws + 33554432;    // [4][2048][2048] bf16 exp'd scores
  float* Pp = (float*)(ws + 33554432); // [4][1024][1024] fp32 Mt partials (dead before Pm)
  u16* Wcat = ws + 50331648;  // [2048][1024]: Mt | Wv^T
  u16* Mt = Wcat;
  u16* Wvt = Wcat + 1048576;
  float* SP = (float*)(ws + 52428800); // [8192][16] per-tile row sums
  float* ST = (float*)(ws + 52953088); // [8192] 1/l

  // all input conversions in one launch
  mega_cvt<<<11264, 256, 0, stream>>>(x, Wq, Wk, Wv, Xb, Wqb, Wkb, Wvt);

  // Mt = Wk * Wq^T, K-split over 4 chunks, then reduce to bf16
  gemm128<4, 4><<<dim3(8, 8, 4), 256, 0, stream>>>(Wkb, Wqb, nullptr, Pp, nullptr);
  reduce_mt_kernel<<<1024, 256, 0, stream>>>(Pp, Mt);

  // fused proj: [Xt | V] = Xb * [Mt | Wvt]^T ; 256 blocks = 1 round, 8-phase
  gemm256_8p<<<dim3(32, 8), 512, 0, stream>>>(Xb, Wcat, Xt, Vt);

  // scores: Pm = exp(Xt * Xb^T * scale), masked; + row-sum partials SP
  gemm128<2, 3><<<dim3(544, 1, 1), 256, 0, stream>>>(Xt, Xb, Pm, nullptr, SP);

  merge_inv_kernel<<<32, 256, 0, stream>>>(SP, ST);

  // PV: out = (Pm . Vt^T) * invl ; 512 blocks, NBUF=3 -> 3 blocks/CU
  gemm128<3, 3><<<dim3(512, 1, 1), 256, 0, stream>>>(Pm, Vt, nullptr, out, ST);
}